// Round 10
// baseline (77.380 us; speedup 1.0000x reference)
//
#include <hip/hip_runtime.h>
#include <math.h>

// ---- problem constants ----
#define L_IN   2560000
#define HOP    512
#define NB     84
#define NF     5000
#define PAD0   6726                    // wl0 = 13453, pad = wl0//2
#define XPLEN  2573452                 // L + 2*PAD0 (valid reflect region)
#define XBLEN2 2637824                 // bf16 taps, mult 2048, pads DMA overreach
#define NTIL   80                      // frame tiles of 64
#define SLOTS  7                       // k-chunk slots per frame tile
#define NBLK   (NTIL*SLOTS)            // 560
#define XB_NB  1288                    // XBLEN2 / 2048
#define AG_NB  502                     // 251*512/256

#define LDS_SZ 70656                   // 69 DMA chunks * 1024; >= 65536 epilogue

// ---- workspace layout (bytes) ----
#define XB_B  0
#define AG_B  5275648                  // XBLEN2*2
#define P_B   7331840                  // AG_B + 251*8192 ; P = 80*5*16KB = 6.55MB
#define CNT_B 13885440                 // P_B + 6553600 ; 80 ints
#define TB_B  13885760                 // 252 ints (wl/pad/fb per bin)

typedef short bf16x8 __attribute__((ext_vector_type(8)));
typedef float f32x16 __attribute__((ext_vector_type(16)));

__device__ inline unsigned short f2bf(float f) {
  unsigned int u = __float_as_uint(f);
  return (unsigned short)((u + 0x7fffu + ((u >> 16) & 1u)) >> 16);
}

__device__ inline void load16(void* l, const void* g) {
  __builtin_amdgcn_global_load_lds((const __attribute__((address_space(1))) void*)g,
                                   (__attribute__((address_space(3))) void*)l, 16, 0, 0);
}

// fused: xb (reflect-pad + bf16, 8/thread), A in per-wave fragment order,
// counter zeroing. Bin params come precomputed from host (tb).
// A layout: [step s][im 2][kk 4][lane 64][j 8] bf16
__global__ __launch_bounds__(256) void k_prep(const float* __restrict__ x,
                                              unsigned short* __restrict__ xb,
                                              unsigned short* __restrict__ Ag,
                                              int* __restrict__ cnt,
                                              const int* __restrict__ tb) {
  if (blockIdx.x < XB_NB) {
    if (blockIdx.x == 0 && threadIdx.x < NTIL) cnt[threadIdx.x] = 0;
    int i8 = (blockIdx.x * 256 + threadIdx.x) * 8;
    bf16x8 o;
    int u0 = i8 - PAD0;
    if (u0 >= 0 && u0 + 8 <= L_IN) {                 // interior fast path
      const float2* p = (const float2*)(x + u0);     // u0 even -> 8B aligned
#pragma unroll
      for (int j = 0; j < 4; ++j) {
        float2 v = p[j];
        o[2 * j]     = (short)f2bf(v.x);
        o[2 * j + 1] = (short)f2bf(v.y);
      }
    } else {
#pragma unroll
      for (int j = 0; j < 8; ++j) {
        int i = i8 + j;
        float v = 0.f;
        if (i < XPLEN) {
          int u = i - PAD0;
          if (u < 0) u = -u;
          else if (u >= L_IN) u = 2 * L_IN - 2 - u;
          v = x[u];
        }
        o[j] = (short)f2bf(v);
      }
    }
    *(bf16x8*)(xb + i8) = o;
  } else {
    int g = (blockIdx.x - XB_NB) * 256 + threadIdx.x;   // < 128512
    int s = g >> 9, w = g & 511;
    int im = w >> 8, kk = (w >> 6) & 3, lane = w & 63;
    int mt  = (s < 211) ? 0 : ((s < 245) ? 1 : 2);
    int mst = (mt == 0) ? 0 : ((mt == 1) ? 211 : 245);
    int kst = (mt == 0) ? 0 : ((mt == 1) ? 5632 : 6528);
    int tap0 = kst + (s - mst) * 64 + kk * 16 + ((lane >> 5) << 3);
    int row = im * 32 + (lane & 31);
    int bin = mt * 32 + (row >> 1);
    bf16x8 vv;
    if (bin >= NB) {
#pragma unroll
      for (int j = 0; j < 8; ++j) vv[j] = 0;
    } else {
      int wl  = tb[bin];
      int pad = tb[NB + bin];
      int fbq = tb[2 * NB + bin];
      int isIm = row & 1;
      float invwl = 1.0f / (float)wl;
#pragma unroll
      for (int j = 0; j < 8; ++j) {
        int n = tap0 + j - (PAD0 - pad);
        float v = 0.f;
        if (n >= 0 && n < wl) {                      // all live bins have wl>=111
          // hann + single-bin DFT; v_sin/v_cos take REVOLUTIONS (ISA §3)
          float wn = 0.5f - 0.5f * __builtin_amdgcn_cosf((float)n * invwl);
          int m = (fbq * n) % wl;                    // fbq*n < 2.3e5, exact
          float rev = (float)m * invwl;              // [0,1)
          float cs = __builtin_amdgcn_cosf(rev);
          float sn = __builtin_amdgcn_sinf(rev);
          v = isIm ? (-wn * sn) : (wn * cs);
        }
        vv[j] = (short)f2bf(v);
      }
    }
    *(bf16x8*)(Ag + ((size_t)s * 4096 + im * 2048 + kk * 512 + lane * 8)) = vv;
  }
}

struct AF { bf16x8 f[2][4]; };

__device__ inline void loadA(AF& a, const char* Ag, int s, int lane) {
  const char* p = Ag + ((size_t)s << 13) + lane * 16;
#pragma unroll
  for (int im = 0; im < 2; ++im)
#pragma unroll
    for (int kk = 0; kk < 4; ++kk)
      a.f[im][kk] = *(const bf16x8*)(p + im * 4096 + kk * 1024);
}

// 4 b128 LDS reads for 32-frame group (l, g); 16B-granular 4-bit XOR swizzle
__device__ inline void readB(bf16x8 bf[4], const char* Bw, int l, int g, int lane) {
  int tb = l * 128 + ((lane >> 5) << 4);
  int ob = (g * 32 + (lane & 31)) * 1024 + tb;
#pragma unroll
  for (int kk = 0; kk < 4; ++kk) {
    int o = ob + kk * 32;
    o ^= ((o >> 10) & 15) << 4;
    bf[kk] = *(const bf16x8*)(Bw + o);
  }
}

__device__ inline void mfma8(const AF& a, const bf16x8 bf[4],
                             f32x16& accA, f32x16& accB) {
  __builtin_amdgcn_s_setprio(1);
#pragma unroll
  for (int kk = 0; kk < 4; ++kk) {
    accA = __builtin_amdgcn_mfma_f32_32x32x16_bf16(a.f[0][kk], bf[kk], accA, 0, 0, 0);
    accB = __builtin_amdgcn_mfma_f32_32x32x16_bf16(a.f[1][kk], bf[kk], accB, 0, 0, 0);
  }
  __builtin_amdgcn_s_setprio(0);
}

// block = 64 rows x 64 frames x one k-chunk; 4 waves K-split, depth-3 A pipe,
// register-double-buffered B reads. mt0 magnitude fused via atomic ticket.
__global__ __launch_bounds__(256, 2) void k_gemm(const unsigned short* __restrict__ Ag,
                                                 const unsigned short* __restrict__ xb,
                                                 float* __restrict__ P,
                                                 int* __restrict__ cnt,
                                                 float* __restrict__ out) {
  extern __shared__ char lds[];
  const int tid = threadIdx.x, lane = tid & 63, wv = tid >> 6;

  // c-major per XCD: LPT tail (c=6 stubs last), bijective; same nt stays on XCD
  int bid = blockIdx.x;
  int xcd = bid & 7, loc = bid >> 3;                // loc 0..69
  int c = loc / 10, ntl = loc - c * 10;
  int nt = xcd * 10 + ntl;
  const int gs_[7] = {0, 43, 85, 127, 169, 211, 245};
  const int ns_[7] = {43, 42, 42, 42, 42, 34, 6};
  const int kb_[7] = {0, 2752, 5440, 8128, 10816, 5632, 6528};
  int gs = gs_[c], ns = ns_[c], kb = kb_[c];
  int nch = (64512 + 128 * ns + 1023) >> 10;        // 1KB DMA chunks

  // ---- stage B window via global_load_lds, pre-swizzled (involutive) source ----
  const char* xsrc = (const char*)xb + (size_t)nt * 65536 + (size_t)kb * 2;
  for (int ci = wv; ci < nch; ci += 4)
    load16(lds + ci * 1024, xsrc + ci * 1024 + ((lane * 16) ^ ((ci & 15) << 4)));
  __builtin_amdgcn_sched_barrier(0);                // keep A-loads below DMAs

  const char* Ab = (const char*)Ag;
  int nks = (ns - wv + 3) >> 2;                     // wave steps: l = wv + 4i
  AF a0, a1, a2;
  int s0 = gs + wv, s1 = gs + wv + 4, s2 = gs + wv + 8;
  loadA(a0, Ab, s0 > 250 ? 250 : s0, lane);
  loadA(a1, Ab, s1 > 250 ? 250 : s1, lane);
  loadA(a2, Ab, s2 > 250 ? 250 : s2, lane);

  f32x16 acc[2][2];
#pragma unroll
  for (int i = 0; i < 2; ++i)
#pragma unroll
    for (int j = 0; j < 2; ++j)
#pragma unroll
      for (int e = 0; e < 16; ++e) acc[i][j][e] = 0.f;

  asm volatile("s_waitcnt vmcnt(24)" ::: "memory"); // DMAs drained (24 A-loads newer)
  __syncthreads();

  bf16x8 bA[4], bB[4];
  readB(bA, lds, wv, 0, lane);                      // prologue: group (step0, g0)

  int i = 0;
  while (i + 3 <= nks) {
    {                                               // step i  (a0)
      int l = wv + 4 * i;
      readB(bB, lds, l, 1, lane);
      mfma8(a0, bA, acc[0][0], acc[1][0]);
      int ln = (i + 1 < nks) ? (wv + 4 * (i + 1)) : l;
      readB(bA, lds, ln, 0, lane);
      mfma8(a0, bB, acc[0][1], acc[1][1]);
      if (i + 3 < nks) loadA(a0, Ab, gs + wv + 4 * (i + 3), lane);
    }
    {                                               // step i+1 (a1)
      int l = wv + 4 * (i + 1);
      readB(bB, lds, l, 1, lane);
      mfma8(a1, bA, acc[0][0], acc[1][0]);
      int ln = (i + 2 < nks) ? (wv + 4 * (i + 2)) : l;
      readB(bA, lds, ln, 0, lane);
      mfma8(a1, bB, acc[0][1], acc[1][1]);
      if (i + 4 < nks) loadA(a1, Ab, gs + wv + 4 * (i + 4), lane);
    }
    {                                               // step i+2 (a2)
      int l = wv + 4 * (i + 2);
      readB(bB, lds, l, 1, lane);
      mfma8(a2, bA, acc[0][0], acc[1][0]);
      int ln = (i + 3 < nks) ? (wv + 4 * (i + 3)) : l;
      readB(bA, lds, ln, 0, lane);
      mfma8(a2, bB, acc[0][1], acc[1][1]);
      if (i + 5 < nks) loadA(a2, Ab, gs + wv + 4 * (i + 5), lane);
    }
    i += 3;
  }
  if (i < nks) {                                    // tail step (a0)
    int l = wv + 4 * i;
    readB(bB, lds, l, 1, lane);
    mfma8(a0, bA, acc[0][0], acc[1][0]);
    int ln = (i + 1 < nks) ? (wv + 4 * (i + 1)) : l;
    readB(bA, lds, ln, 0, lane);
    mfma8(a0, bB, acc[0][1], acc[1][1]);
    if (i + 1 < nks) {                              // tail step (a1)
      int l1 = wv + 4 * (i + 1);
      readB(bB, lds, l1, 1, lane);
      mfma8(a1, bA, acc[0][0], acc[1][0]);
      int l2 = (i + 2 < nks) ? (wv + 4 * (i + 2)) : l1;
      readB(bA, lds, l2, 0, lane);
      mfma8(a1, bB, acc[0][1], acc[1][1]);
      if (i + 2 < nks) {                            // tail step (a2)
        readB(bB, lds, wv + 4 * (i + 2), 1, lane);
        mfma8(a2, bA, acc[0][0], acc[1][0]);
        mfma8(a2, bB, acc[0][1], acc[1][1]);
      }
    }
  }

  // ---- epilogue: cross-wave reduce in LDS (window dead now) ----
  __syncthreads();
  float* Cw = (float*)(lds + wv * 16384);
#pragma unroll
  for (int im = 0; im < 2; ++im)
#pragma unroll
    for (int in_ = 0; in_ < 2; ++in_) {
      f32x16 v = acc[im][in_];
      int col = in_ * 32 + (lane & 31);
      int rb  = im * 32 + ((lane >> 5) << 2);
#pragma unroll
      for (int r = 0; r < 16; ++r) {
        int row = rb + (r & 3) + 8 * (r >> 2);
        Cw[row * 64 + col] = v[r];
      }
    }
  __syncthreads();
  const float* L0 = (const float*)lds;
  if (c < 5) {                                      // mt0: partial tile to P
    float* Pb = P + ((size_t)(nt * 5 + c) << 12);
#pragma unroll
    for (int e = 0; e < 16; ++e) {
      int idx = e * 256 + tid;
      Pb[idx] = L0[idx] + L0[idx + 4096] + L0[idx + 8192] + L0[idx + 12288];
    }
    __threadfence();                                // release P writes
    __syncthreads();
    int* flag = (int*)(lds + 69632);
    if (tid == 0) *flag = atomicAdd(&cnt[nt], 1);
    __syncthreads();
    if (*flag == 4) {                               // 5th arriver: fused magnitude
      __threadfence();                              // acquire other blocks' P
      const float* P0 = P + ((size_t)(nt * 5) << 12);
#pragma unroll
      for (int e = 0; e < 8; ++e) {
        int p = e * 256 + tid;                      // 2048 (bin,col) pairs
        int bl = p >> 6, fl = p & 63;
        float re = 0.f, iv = 0.f;
#pragma unroll
        for (int cc = 0; cc < 5; ++cc) {
          re += P0[cc * 4096 + (2 * bl) * 64 + fl];
          iv += P0[cc * 4096 + (2 * bl + 1) * 64 + fl];
        }
        int col = nt * 64 + fl;
        if (col < NF) out[(size_t)bl * NF + col] = sqrtf(re * re + iv * iv);
      }
    }
  } else {                                          // mt1/mt2: direct magnitude
    int bb = (c == 5) ? 32 : 64;
#pragma unroll
    for (int e = 0; e < 8; ++e) {
      int p = e * 256 + tid;                        // 2048 (bin,col) pairs
      int bl = p >> 6, fl = p & 63;
      int r0 = (bl * 2) * 64 + fl, r1 = r0 + 64;
      float re = L0[r0] + L0[r0 + 4096] + L0[r0 + 8192] + L0[r0 + 12288];
      float iv = L0[r1] + L0[r1 + 4096] + L0[r1 + 8192] + L0[r1 + 12288];
      int b = bb + bl, col = nt * 64 + fl;
      if (b < NB && col < NF)
        out[(size_t)b * NF + col] = sqrtf(re * re + iv * iv);
    }
  }
}

extern "C" void kernel_launch(void* const* d_in, const int* in_sizes, int n_in,
                              void* d_out, int out_size, void* d_ws, size_t ws_size,
                              hipStream_t stream) {
  const float* x = (const float*)d_in[0];
  char* ws = (char*)d_ws;
  unsigned short* xb = (unsigned short*)(ws + XB_B);
  unsigned short* Ag = (unsigned short*)(ws + AG_B);
  float* P           = (float*)(ws + P_B);
  int* cnt           = (int*)(ws + CNT_B);
  int* tbd           = (int*)(ws + TB_B);
  float* out = (float*)d_out;

  // host-side bin tables (exact reference formulas, f64); static so the
  // graph-captured H2D memcpy source stays valid across replays
  static int h_tb[3 * NB];
  {
    double q = 1.0 / (pow(2.0, 1.0 / 12.0) - 1.0);
    for (int b = 0; b < NB; ++b) {
      double freq = 20.0 * pow(2.0, (double)b / 12.0);
      int wl = (int)(16000.0 * q / freq);
      if (wl > L_IN / 4) wl = L_IN / 4;
      int pad = wl >> 1;
      int fb = (int)(freq * (double)wl / 16000.0);
      if (fb > wl / 2) fb = wl / 2;
      h_tb[b] = wl; h_tb[NB + b] = pad; h_tb[2 * NB + b] = fb;
    }
  }
  hipMemcpyAsync(tbd, h_tb, sizeof(h_tb), hipMemcpyHostToDevice, stream);

  hipFuncSetAttribute((const void*)k_gemm,
                      hipFuncAttributeMaxDynamicSharedMemorySize, LDS_SZ);

  hipLaunchKernelGGL(k_prep, dim3(XB_NB + AG_NB), dim3(256), 0, stream, x, xb, Ag, cnt, tbd);
  hipLaunchKernelGGL(k_gemm, dim3(NBLK), dim3(256), LDS_SZ, stream, Ag, xb, P, cnt, out);
}

// Round 11
// 35.237 us; speedup vs baseline: 2.1960x; 2.1960x over previous
//
#include <hip/hip_runtime.h>
#include <math.h>

// ---- problem constants ----
#define L_IN   2560000
#define HOP    512
#define NB     84
#define NF     5000
#define PAD0   6726                    // wl0 = 13453, pad = wl0//2
#define XPLEN  2573452                 // L + 2*PAD0 (valid reflect region)
#define XBLEN2 2637824                 // bf16 taps, mult 2048, pads DMA overreach
#define NTIL   80                      // frame tiles of 64
#define SLOTS  7                       // k-chunk slots per frame tile
#define NBLK   (NTIL*SLOTS)            // 560
#define XB_NB  1288                    // XBLEN2 / 2048
#define AG_NB  502                     // 251*512/256

#define LDS_SZ 70656                   // 69 DMA chunks * 1024; >= 65536 epilogue

// ---- workspace layout (bytes) ----
#define XB_B 0
#define AG_B 5275648                   // XBLEN2*2
#define P_B  7331840                   // AG_B + 251*8192 ; P = 80*5*16KB = 6.55MB
#define TB_B 13885440                  // 252 ints (wl/pad/fb per bin)

typedef short bf16x8 __attribute__((ext_vector_type(8)));
typedef float f32x16 __attribute__((ext_vector_type(16)));

__device__ inline unsigned short f2bf(float f) {
  unsigned int u = __float_as_uint(f);
  return (unsigned short)((u + 0x7fffu + ((u >> 16) & 1u)) >> 16);
}

__device__ inline void load16(void* l, const void* g) {
  __builtin_amdgcn_global_load_lds((const __attribute__((address_space(1))) void*)g,
                                   (__attribute__((address_space(3))) void*)l, 16, 0, 0);
}

// fused: xb (reflect-pad + bf16, 8/thread) and A in per-wave fragment order.
// Bin params precomputed on host (tb). A: [step s][im 2][kk 4][lane 64][j 8]
__global__ __launch_bounds__(256) void k_prep(const float* __restrict__ x,
                                              unsigned short* __restrict__ xb,
                                              unsigned short* __restrict__ Ag,
                                              const int* __restrict__ tb) {
  if (blockIdx.x < XB_NB) {
    int i8 = (blockIdx.x * 256 + threadIdx.x) * 8;
    bf16x8 o;
    int u0 = i8 - PAD0;
    if (u0 >= 0 && u0 + 8 <= L_IN) {                 // interior fast path
      const float2* p = (const float2*)(x + u0);     // u0 even -> 8B aligned
#pragma unroll
      for (int j = 0; j < 4; ++j) {
        float2 v = p[j];
        o[2 * j]     = (short)f2bf(v.x);
        o[2 * j + 1] = (short)f2bf(v.y);
      }
    } else {
#pragma unroll
      for (int j = 0; j < 8; ++j) {
        int i = i8 + j;
        float v = 0.f;
        if (i < XPLEN) {
          int u = i - PAD0;
          if (u < 0) u = -u;
          else if (u >= L_IN) u = 2 * L_IN - 2 - u;
          v = x[u];
        }
        o[j] = (short)f2bf(v);
      }
    }
    *(bf16x8*)(xb + i8) = o;
  } else {
    int g = (blockIdx.x - XB_NB) * 256 + threadIdx.x;   // < 128512
    int s = g >> 9, w = g & 511;
    int im = w >> 8, kk = (w >> 6) & 3, lane = w & 63;
    int mt  = (s < 211) ? 0 : ((s < 245) ? 1 : 2);
    int mst = (mt == 0) ? 0 : ((mt == 1) ? 211 : 245);
    int kst = (mt == 0) ? 0 : ((mt == 1) ? 5632 : 6528);
    int tap0 = kst + (s - mst) * 64 + kk * 16 + ((lane >> 5) << 3);
    int row = im * 32 + (lane & 31);
    int bin = mt * 32 + (row >> 1);
    bf16x8 vv;
    if (bin >= NB) {
#pragma unroll
      for (int j = 0; j < 8; ++j) vv[j] = 0;
    } else {
      int wl  = tb[bin];
      int pad = tb[NB + bin];
      int fbq = tb[2 * NB + bin];
      int isIm = row & 1;
      float invwl = 1.0f / (float)wl;
#pragma unroll
      for (int j = 0; j < 8; ++j) {
        int n = tap0 + j - (PAD0 - pad);
        float v = 0.f;
        if (n >= 0 && n < wl) {                      // all live bins have wl>=111
          // hann + single-bin DFT; v_sin/v_cos take REVOLUTIONS (verified r10)
          float wn = 0.5f - 0.5f * __builtin_amdgcn_cosf((float)n * invwl);
          int m = (fbq * n) % wl;                    // fbq*n < 2.3e5, exact
          float rev = (float)m * invwl;              // [0,1)
          float cs = __builtin_amdgcn_cosf(rev);
          float sn = __builtin_amdgcn_sinf(rev);
          v = isIm ? (-wn * sn) : (wn * cs);
        }
        vv[j] = (short)f2bf(v);
      }
    }
    *(bf16x8*)(Ag + ((size_t)s * 4096 + im * 2048 + kk * 512 + lane * 8)) = vv;
  }
}

struct AF { bf16x8 f[2][4]; };

__device__ inline void loadA(AF& a, const char* Ag, int s, int lane) {
  const char* p = Ag + ((size_t)s << 13) + lane * 16;
#pragma unroll
  for (int im = 0; im < 2; ++im)
#pragma unroll
    for (int kk = 0; kk < 4; ++kk)
      a.f[im][kk] = *(const bf16x8*)(p + im * 4096 + kk * 1024);
}

// 4 b128 LDS reads for 32-frame group (l, g); 16B-granular 4-bit XOR swizzle
__device__ inline void readB(bf16x8 bf[4], const char* Bw, int l, int g, int lane) {
  int tb = l * 128 + ((lane >> 5) << 4);
  int ob = (g * 32 + (lane & 31)) * 1024 + tb;
#pragma unroll
  for (int kk = 0; kk < 4; ++kk) {
    int o = ob + kk * 32;
    o ^= ((o >> 10) & 15) << 4;
    bf[kk] = *(const bf16x8*)(Bw + o);
  }
}

__device__ inline void mfma8(const AF& a, const bf16x8 bf[4],
                             f32x16& accA, f32x16& accB) {
  __builtin_amdgcn_s_setprio(1);
#pragma unroll
  for (int kk = 0; kk < 4; ++kk) {
    accA = __builtin_amdgcn_mfma_f32_32x32x16_bf16(a.f[0][kk], bf[kk], accA, 0, 0, 0);
    accB = __builtin_amdgcn_mfma_f32_32x32x16_bf16(a.f[1][kk], bf[kk], accB, 0, 0, 0);
  }
  __builtin_amdgcn_s_setprio(0);
}

// block = 64 rows x 64 frames x one k-chunk; 4 waves K-split, depth-3 A pipe,
// register-double-buffered B reads. No cross-block sync (r10 lesson: device-
// scope fences cost an L2 writeback per block — a separate dispatch is cheaper).
__global__ __launch_bounds__(256, 2) void k_gemm(const unsigned short* __restrict__ Ag,
                                                 const unsigned short* __restrict__ xb,
                                                 float* __restrict__ P,
                                                 float* __restrict__ out) {
  extern __shared__ char lds[];
  const int tid = threadIdx.x, lane = tid & 63, wv = tid >> 6;

  // c-major per XCD: LPT tail (c=6 stubs dispatched last), bijective
  int bid = blockIdx.x;
  int xcd = bid & 7, loc = bid >> 3;                // loc 0..69
  int c = loc / 10, ntl = loc - c * 10;
  int nt = xcd * 10 + ntl;
  const int gs_[7] = {0, 43, 85, 127, 169, 211, 245};
  const int ns_[7] = {43, 42, 42, 42, 42, 34, 6};
  const int kb_[7] = {0, 2752, 5440, 8128, 10816, 5632, 6528};
  int gs = gs_[c], ns = ns_[c], kb = kb_[c];
  int nch = (64512 + 128 * ns + 1023) >> 10;        // 1KB DMA chunks

  // ---- stage B window via global_load_lds, pre-swizzled (involutive) source ----
  const char* xsrc = (const char*)xb + (size_t)nt * 65536 + (size_t)kb * 2;
  for (int ci = wv; ci < nch; ci += 4)
    load16(lds + ci * 1024, xsrc + ci * 1024 + ((lane * 16) ^ ((ci & 15) << 4)));
  __builtin_amdgcn_sched_barrier(0);                // keep A-loads below DMAs

  const char* Ab = (const char*)Ag;
  int nks = (ns - wv + 3) >> 2;                     // wave steps: l = wv + 4i
  AF a0, a1, a2;
  int s0 = gs + wv, s1 = gs + wv + 4, s2 = gs + wv + 8;
  loadA(a0, Ab, s0 > 250 ? 250 : s0, lane);
  loadA(a1, Ab, s1 > 250 ? 250 : s1, lane);
  loadA(a2, Ab, s2 > 250 ? 250 : s2, lane);

  f32x16 acc[2][2];
#pragma unroll
  for (int i = 0; i < 2; ++i)
#pragma unroll
    for (int j = 0; j < 2; ++j)
#pragma unroll
      for (int e = 0; e < 16; ++e) acc[i][j][e] = 0.f;

  asm volatile("s_waitcnt vmcnt(24)" ::: "memory"); // DMAs drained (24 A-loads newer)
  __syncthreads();

  bf16x8 bA[4], bB[4];
  readB(bA, lds, wv, 0, lane);                      // prologue: group (step0, g0)

  int i = 0;
  while (i + 3 <= nks) {
    {                                               // step i  (a0)
      int l = wv + 4 * i;
      readB(bB, lds, l, 1, lane);
      mfma8(a0, bA, acc[0][0], acc[1][0]);
      int ln = (i + 1 < nks) ? (wv + 4 * (i + 1)) : l;
      readB(bA, lds, ln, 0, lane);
      mfma8(a0, bB, acc[0][1], acc[1][1]);
      if (i + 3 < nks) loadA(a0, Ab, gs + wv + 4 * (i + 3), lane);
    }
    {                                               // step i+1 (a1)
      int l = wv + 4 * (i + 1);
      readB(bB, lds, l, 1, lane);
      mfma8(a1, bA, acc[0][0], acc[1][0]);
      int ln = (i + 2 < nks) ? (wv + 4 * (i + 2)) : l;
      readB(bA, lds, ln, 0, lane);
      mfma8(a1, bB, acc[0][1], acc[1][1]);
      if (i + 4 < nks) loadA(a1, Ab, gs + wv + 4 * (i + 4), lane);
    }
    {                                               // step i+2 (a2)
      int l = wv + 4 * (i + 2);
      readB(bB, lds, l, 1, lane);
      mfma8(a2, bA, acc[0][0], acc[1][0]);
      int ln = (i + 3 < nks) ? (wv + 4 * (i + 3)) : l;
      readB(bA, lds, ln, 0, lane);
      mfma8(a2, bB, acc[0][1], acc[1][1]);
      if (i + 5 < nks) loadA(a2, Ab, gs + wv + 4 * (i + 5), lane);
    }
    i += 3;
  }
  if (i < nks) {                                    // tail step (a0)
    int l = wv + 4 * i;
    readB(bB, lds, l, 1, lane);
    mfma8(a0, bA, acc[0][0], acc[1][0]);
    int ln = (i + 1 < nks) ? (wv + 4 * (i + 1)) : l;
    readB(bA, lds, ln, 0, lane);
    mfma8(a0, bB, acc[0][1], acc[1][1]);
    if (i + 1 < nks) {                              // tail step (a1)
      int l1 = wv + 4 * (i + 1);
      readB(bB, lds, l1, 1, lane);
      mfma8(a1, bA, acc[0][0], acc[1][0]);
      int l2 = (i + 2 < nks) ? (wv + 4 * (i + 2)) : l1;
      readB(bA, lds, l2, 0, lane);
      mfma8(a1, bB, acc[0][1], acc[1][1]);
      if (i + 2 < nks) {                            // tail step (a2)
        readB(bB, lds, wv + 4 * (i + 2), 1, lane);
        mfma8(a2, bA, acc[0][0], acc[1][0]);
        mfma8(a2, bB, acc[0][1], acc[1][1]);
      }
    }
  }

  // ---- epilogue: cross-wave reduce in LDS (window dead now) ----
  __syncthreads();
  float* Cw = (float*)(lds + wv * 16384);
#pragma unroll
  for (int im = 0; im < 2; ++im)
#pragma unroll
    for (int in_ = 0; in_ < 2; ++in_) {
      f32x16 v = acc[im][in_];
      int col = in_ * 32 + (lane & 31);
      int rb  = im * 32 + ((lane >> 5) << 2);
#pragma unroll
      for (int r = 0; r < 16; ++r) {
        int row = rb + (r & 3) + 8 * (r >> 2);
        Cw[row * 64 + col] = v[r];
      }
    }
  __syncthreads();
  const float* L0 = (const float*)lds;
  if (c < 5) {                                      // mt0: partial tile to P
    float* Pb = P + ((size_t)(nt * 5 + c) << 12);
#pragma unroll
    for (int e = 0; e < 16; ++e) {
      int idx = e * 256 + tid;
      Pb[idx] = L0[idx] + L0[idx + 4096] + L0[idx + 8192] + L0[idx + 12288];
    }
  } else {                                          // mt1/mt2: direct magnitude
    int bb = (c == 5) ? 32 : 64;
#pragma unroll
    for (int e = 0; e < 8; ++e) {
      int p = e * 256 + tid;                        // 2048 (bin,col) pairs
      int bl = p >> 6, fl = p & 63;
      int r0 = (bl * 2) * 64 + fl, r1 = r0 + 64;
      float re = L0[r0] + L0[r0 + 4096] + L0[r0 + 8192] + L0[r0 + 12288];
      float iv = L0[r1] + L0[r1 + 4096] + L0[r1 + 8192] + L0[r1 + 12288];
      int b = bb + bl, col = nt * 64 + fl;
      if (b < NB && col < NF)
        out[(size_t)b * NF + col] = sqrtf(re * re + iv * iv);
    }
  }
}

// reduce mt0 partials over 5 k-chunks + magnitude (bins 0..31)
__global__ __launch_bounds__(256) void k_mag(const float* __restrict__ P,
                                             float* __restrict__ out) {
  int col = blockIdx.x * 256 + threadIdx.x;
  int b = blockIdx.y;                               // 0..31
  if (col >= NF) return;
  int nt = col >> 6, fl = col & 63;
  const float* Pt = P + ((size_t)(nt * 5) << 12);
  float re = 0.f, iv = 0.f;
#pragma unroll
  for (int c = 0; c < 5; ++c) {
    const float* Pb = Pt + ((size_t)c << 12);
    re += Pb[(2 * b) * 64 + fl];
    iv += Pb[(2 * b + 1) * 64 + fl];
  }
  out[(size_t)b * NF + col] = sqrtf(re * re + iv * iv);
}

extern "C" void kernel_launch(void* const* d_in, const int* in_sizes, int n_in,
                              void* d_out, int out_size, void* d_ws, size_t ws_size,
                              hipStream_t stream) {
  const float* x = (const float*)d_in[0];
  char* ws = (char*)d_ws;
  unsigned short* xb = (unsigned short*)(ws + XB_B);
  unsigned short* Ag = (unsigned short*)(ws + AG_B);
  float* P           = (float*)(ws + P_B);
  int* tbd           = (int*)(ws + TB_B);
  float* out = (float*)d_out;

  // host-side bin tables (exact reference formulas, f64); static so the
  // graph-captured H2D memcpy source stays valid across replays
  static int h_tb[3 * NB];
  {
    double q = 1.0 / (pow(2.0, 1.0 / 12.0) - 1.0);
    for (int b = 0; b < NB; ++b) {
      double freq = 20.0 * pow(2.0, (double)b / 12.0);
      int wl = (int)(16000.0 * q / freq);
      if (wl > L_IN / 4) wl = L_IN / 4;
      int pad = wl >> 1;
      int fb = (int)(freq * (double)wl / 16000.0);
      if (fb > wl / 2) fb = wl / 2;
      h_tb[b] = wl; h_tb[NB + b] = pad; h_tb[2 * NB + b] = fb;
    }
  }
  hipMemcpyAsync(tbd, h_tb, sizeof(h_tb), hipMemcpyHostToDevice, stream);

  hipFuncSetAttribute((const void*)k_gemm,
                      hipFuncAttributeMaxDynamicSharedMemorySize, LDS_SZ);

  hipLaunchKernelGGL(k_prep, dim3(XB_NB + AG_NB), dim3(256), 0, stream, x, xb, Ag, tbd);
  hipLaunchKernelGGL(k_gemm, dim3(NBLK), dim3(256), LDS_SZ, stream, Ag, xb, P, out);
  hipLaunchKernelGGL(k_mag, dim3(20, 32), dim3(256), 0, stream, P, out);
}

// Round 12
// 29.510 us; speedup vs baseline: 2.6222x; 1.1941x over previous
//
#include <hip/hip_runtime.h>
#include <math.h>

// ---- problem constants ----
#define L_IN   2560000
#define HOP    512
#define NB     84
#define NF     5000
#define PAD0   6726                    // wl0 = 13453, pad = wl0//2
#define XPLEN  2573452                 // L + 2*PAD0 (valid reflect region)
#define XBLEN2 2637824                 // bf16 taps, mult 2048, pads DMA overreach
#define NTIL   80                      // frame tiles of 64
#define SLOTS  7                       // k-chunk slots per frame tile
#define NBLK   (NTIL*SLOTS)            // 560
#define XB_NB  1288                    // XBLEN2 / 2048
#define AG_NB  502                     // 251*512/256

#define LDS_SZ 70656                   // 69 DMA chunks * 1024; >= 65536 epilogue

// ---- workspace layout (bytes) ----
#define XB_B 0
#define AG_B 5275648                   // XBLEN2*2
#define P_B  7331840                   // AG_B + 251*8192 ; P = 80*5*16KB = 6.55MB

typedef short bf16x8 __attribute__((ext_vector_type(8)));
typedef float f32x16 __attribute__((ext_vector_type(16)));

__device__ inline unsigned short f2bf(float f) {
  unsigned int u = __float_as_uint(f);
  return (unsigned short)((u + 0x7fffu + ((u >> 16) & 1u)) >> 16);
}

__device__ inline void load16(void* l, const void* g) {
  __builtin_amdgcn_global_load_lds((const __attribute__((address_space(1))) void*)g,
                                   (__attribute__((address_space(3))) void*)l, 16, 0, 0);
}

// fused: xb (reflect-pad + bf16, 8/thread) and A in per-wave fragment order.
// Bin params computed once per block (16 threads, f64) -> LDS broadcast;
// trig via v_sin/v_cos in revolutions (verified r10/r11).
// A layout: [step s][im 2][kk 4][lane 64][j 8] bf16
__global__ __launch_bounds__(256) void k_prep(const float* __restrict__ x,
                                              unsigned short* __restrict__ xb,
                                              unsigned short* __restrict__ Ag) {
  __shared__ int s_wl[16], s_pad[16], s_fb[16];
  if (blockIdx.x < XB_NB) {
    int i8 = (blockIdx.x * 256 + threadIdx.x) * 8;
    bf16x8 o;
    int u0 = i8 - PAD0;
    if (u0 >= 0 && u0 + 8 <= L_IN) {                 // interior fast path
      const float2* p = (const float2*)(x + u0);     // u0 even -> 8B aligned
#pragma unroll
      for (int j = 0; j < 4; ++j) {
        float2 v = p[j];
        o[2 * j]     = (short)f2bf(v.x);
        o[2 * j + 1] = (short)f2bf(v.y);
      }
    } else {
#pragma unroll
      for (int j = 0; j < 8; ++j) {
        int i = i8 + j;
        float v = 0.f;
        if (i < XPLEN) {
          int u = i - PAD0;
          if (u < 0) u = -u;
          else if (u >= L_IN) u = 2 * L_IN - 2 - u;
          v = x[u];
        }
        o[j] = (short)f2bf(v);
      }
    }
    *(bf16x8*)(xb + i8) = o;
  } else {
    int g = (blockIdx.x - XB_NB) * 256 + threadIdx.x;   // < 128512
    int s = g >> 9, w = g & 511;
    int im = w >> 8, kk = (w >> 6) & 3, lane = w & 63;  // im uniform per block
    int mt  = (s < 211) ? 0 : ((s < 245) ? 1 : 2);
    int mst = (mt == 0) ? 0 : ((mt == 1) ? 211 : 245);
    int kst = (mt == 0) ? 0 : ((mt == 1) ? 5632 : 6528);
    int tap0 = kst + (s - mst) * 64 + kk * 16 + ((lane >> 5) << 3);
    int bin0 = mt * 32 + im * 16;                    // block covers 16 bins
    if (threadIdx.x < 16) {
      int bin = bin0 + threadIdx.x;
      int wl = 0, pad = 0, fb = 0;
      if (bin < NB) {
        double q    = 1.0 / (pow(2.0, 1.0 / 12.0) - 1.0);
        double freq = 20.0 * pow(2.0, (double)bin / 12.0);
        wl = (int)(16000.0 * q / freq);
        if (wl > L_IN / 4) wl = L_IN / 4;
        pad = wl >> 1;
        fb = (int)(freq * (double)wl / 16000.0);
        if (fb > wl / 2) fb = wl / 2;
      }
      s_wl[threadIdx.x] = wl; s_pad[threadIdx.x] = pad; s_fb[threadIdx.x] = fb;
    }
    __syncthreads();
    int bi  = (lane & 31) >> 1;                      // bin index within block
    int wl  = s_wl[bi], pad = s_pad[bi], fbq = s_fb[bi];
    int isIm = lane & 1;
    bf16x8 vv;
    if (wl == 0) {
#pragma unroll
      for (int j = 0; j < 8; ++j) vv[j] = 0;
    } else {
      float invwl = 1.0f / (float)wl;
#pragma unroll
      for (int j = 0; j < 8; ++j) {
        int n = tap0 + j - (PAD0 - pad);
        float v = 0.f;
        if (n >= 0 && n < wl) {                      // all live bins have wl>=111
          float wn = 0.5f - 0.5f * __builtin_amdgcn_cosf((float)n * invwl);
          int m = (fbq * n) % wl;                    // fbq*n < 2.3e5, exact
          float rev = (float)m * invwl;              // [0,1)
          float cs = __builtin_amdgcn_cosf(rev);
          float sn = __builtin_amdgcn_sinf(rev);
          v = isIm ? (-wn * sn) : (wn * cs);
        }
        vv[j] = (short)f2bf(v);
      }
    }
    *(bf16x8*)(Ag + ((size_t)s * 4096 + im * 2048 + kk * 512 + lane * 8)) = vv;
  }
}

struct AF { bf16x8 f[2][4]; };

__device__ inline void loadA(AF& a, const char* Ag, int s, int lane) {
  const char* p = Ag + ((size_t)s << 13) + lane * 16;
#pragma unroll
  for (int im = 0; im < 2; ++im)
#pragma unroll
    for (int kk = 0; kk < 4; ++kk)
      a.f[im][kk] = *(const bf16x8*)(p + im * 4096 + kk * 1024);
}

// 4 b128 LDS reads for 32-frame group (l, g); 16B-granular 4-bit XOR swizzle
__device__ inline void readB(bf16x8 bf[4], const char* Bw, int l, int g, int lane) {
  int tb = l * 128 + ((lane >> 5) << 4);
  int ob = (g * 32 + (lane & 31)) * 1024 + tb;
#pragma unroll
  for (int kk = 0; kk < 4; ++kk) {
    int o = ob + kk * 32;
    o ^= ((o >> 10) & 15) << 4;
    bf[kk] = *(const bf16x8*)(Bw + o);
  }
}

__device__ inline void mfma8(const AF& a, const bf16x8 bf[4],
                             f32x16& accA, f32x16& accB) {
  __builtin_amdgcn_s_setprio(1);
#pragma unroll
  for (int kk = 0; kk < 4; ++kk) {
    accA = __builtin_amdgcn_mfma_f32_32x32x16_bf16(a.f[0][kk], bf[kk], accA, 0, 0, 0);
    accB = __builtin_amdgcn_mfma_f32_32x32x16_bf16(a.f[1][kk], bf[kk], accB, 0, 0, 0);
  }
  __builtin_amdgcn_s_setprio(0);
}

// block = 64 rows x 64 frames x one k-chunk; 4 waves K-split, depth-3 A pipe,
// register-double-buffered B reads. No cross-block sync (r10 lesson: device-
// scope fences cost an L2 writeback per block — a separate dispatch is cheaper).
__global__ __launch_bounds__(256, 2) void k_gemm(const unsigned short* __restrict__ Ag,
                                                 const unsigned short* __restrict__ xb,
                                                 float* __restrict__ P,
                                                 float* __restrict__ out) {
  extern __shared__ char lds[];
  const int tid = threadIdx.x, lane = tid & 63, wv = tid >> 6;

  // c-major per XCD: LPT tail (c=6 stubs dispatched last), bijective
  int bid = blockIdx.x;
  int xcd = bid & 7, loc = bid >> 3;                // loc 0..69
  int c = loc / 10, ntl = loc - c * 10;
  int nt = xcd * 10 + ntl;
  const int gs_[7] = {0, 43, 85, 127, 169, 211, 245};
  const int ns_[7] = {43, 42, 42, 42, 42, 34, 6};
  const int kb_[7] = {0, 2752, 5440, 8128, 10816, 5632, 6528};
  int gs = gs_[c], ns = ns_[c], kb = kb_[c];
  int nch = (64512 + 128 * ns + 1023) >> 10;        // 1KB DMA chunks

  // ---- stage B window via global_load_lds, pre-swizzled (involutive) source ----
  const char* xsrc = (const char*)xb + (size_t)nt * 65536 + (size_t)kb * 2;
  for (int ci = wv; ci < nch; ci += 4)
    load16(lds + ci * 1024, xsrc + ci * 1024 + ((lane * 16) ^ ((ci & 15) << 4)));
  __builtin_amdgcn_sched_barrier(0);                // keep A-loads below DMAs

  const char* Ab = (const char*)Ag;
  int nks = (ns - wv + 3) >> 2;                     // wave steps: l = wv + 4i
  AF a0, a1, a2;
  int s0 = gs + wv, s1 = gs + wv + 4, s2 = gs + wv + 8;
  loadA(a0, Ab, s0 > 250 ? 250 : s0, lane);
  loadA(a1, Ab, s1 > 250 ? 250 : s1, lane);
  loadA(a2, Ab, s2 > 250 ? 250 : s2, lane);

  f32x16 acc[2][2];
#pragma unroll
  for (int i = 0; i < 2; ++i)
#pragma unroll
    for (int j = 0; j < 2; ++j)
#pragma unroll
      for (int e = 0; e < 16; ++e) acc[i][j][e] = 0.f;

  asm volatile("s_waitcnt vmcnt(24)" ::: "memory"); // DMAs drained (24 A-loads newer)
  __syncthreads();

  bf16x8 bA[4], bB[4];
  readB(bA, lds, wv, 0, lane);                      // prologue: group (step0, g0)

  int i = 0;
  while (i + 3 <= nks) {
    {                                               // step i  (a0)
      int l = wv + 4 * i;
      readB(bB, lds, l, 1, lane);
      mfma8(a0, bA, acc[0][0], acc[1][0]);
      int ln = (i + 1 < nks) ? (wv + 4 * (i + 1)) : l;
      readB(bA, lds, ln, 0, lane);
      mfma8(a0, bB, acc[0][1], acc[1][1]);
      if (i + 3 < nks) loadA(a0, Ab, gs + wv + 4 * (i + 3), lane);
    }
    {                                               // step i+1 (a1)
      int l = wv + 4 * (i + 1);
      readB(bB, lds, l, 1, lane);
      mfma8(a1, bA, acc[0][0], acc[1][0]);
      int ln = (i + 2 < nks) ? (wv + 4 * (i + 2)) : l;
      readB(bA, lds, ln, 0, lane);
      mfma8(a1, bB, acc[0][1], acc[1][1]);
      if (i + 4 < nks) loadA(a1, Ab, gs + wv + 4 * (i + 4), lane);
    }
    {                                               // step i+2 (a2)
      int l = wv + 4 * (i + 2);
      readB(bB, lds, l, 1, lane);
      mfma8(a2, bA, acc[0][0], acc[1][0]);
      int ln = (i + 3 < nks) ? (wv + 4 * (i + 3)) : l;
      readB(bA, lds, ln, 0, lane);
      mfma8(a2, bB, acc[0][1], acc[1][1]);
      if (i + 5 < nks) loadA(a2, Ab, gs + wv + 4 * (i + 5), lane);
    }
    i += 3;
  }
  if (i < nks) {                                    // tail step (a0)
    int l = wv + 4 * i;
    readB(bB, lds, l, 1, lane);
    mfma8(a0, bA, acc[0][0], acc[1][0]);
    int ln = (i + 1 < nks) ? (wv + 4 * (i + 1)) : l;
    readB(bA, lds, ln, 0, lane);
    mfma8(a0, bB, acc[0][1], acc[1][1]);
    if (i + 1 < nks) {                              // tail step (a1)
      int l1 = wv + 4 * (i + 1);
      readB(bB, lds, l1, 1, lane);
      mfma8(a1, bA, acc[0][0], acc[1][0]);
      int l2 = (i + 2 < nks) ? (wv + 4 * (i + 2)) : l1;
      readB(bA, lds, l2, 0, lane);
      mfma8(a1, bB, acc[0][1], acc[1][1]);
      if (i + 2 < nks) {                            // tail step (a2)
        readB(bB, lds, wv + 4 * (i + 2), 1, lane);
        mfma8(a2, bA, acc[0][0], acc[1][0]);
        mfma8(a2, bB, acc[0][1], acc[1][1]);
      }
    }
  }

  // ---- epilogue: cross-wave reduce in LDS (window dead now) ----
  __syncthreads();
  float* Cw = (float*)(lds + wv * 16384);
#pragma unroll
  for (int im = 0; im < 2; ++im)
#pragma unroll
    for (int in_ = 0; in_ < 2; ++in_) {
      f32x16 v = acc[im][in_];
      int col = in_ * 32 + (lane & 31);
      int rb  = im * 32 + ((lane >> 5) << 2);
#pragma unroll
      for (int r = 0; r < 16; ++r) {
        int row = rb + (r & 3) + 8 * (r >> 2);
        Cw[row * 64 + col] = v[r];
      }
    }
  __syncthreads();
  const float* L0 = (const float*)lds;
  if (c < 5) {                                      // mt0: partial tile to P
    float* Pb = P + ((size_t)(nt * 5 + c) << 12);
#pragma unroll
    for (int e = 0; e < 16; ++e) {
      int idx = e * 256 + tid;
      Pb[idx] = L0[idx] + L0[idx + 4096] + L0[idx + 8192] + L0[idx + 12288];
    }
  } else {                                          // mt1/mt2: direct magnitude
    int bb = (c == 5) ? 32 : 64;
#pragma unroll
    for (int e = 0; e < 8; ++e) {
      int p = e * 256 + tid;                        // 2048 (bin,col) pairs
      int bl = p >> 6, fl = p & 63;
      int r0 = (bl * 2) * 64 + fl, r1 = r0 + 64;
      float re = L0[r0] + L0[r0 + 4096] + L0[r0 + 8192] + L0[r0 + 12288];
      float iv = L0[r1] + L0[r1 + 4096] + L0[r1 + 8192] + L0[r1 + 12288];
      int b = bb + bl, col = nt * 64 + fl;
      if (b < NB && col < NF)
        out[(size_t)b * NF + col] = sqrtf(re * re + iv * iv);
    }
  }
}

// reduce mt0 partials over 5 k-chunks + magnitude (bins 0..31)
__global__ __launch_bounds__(256) void k_mag(const float* __restrict__ P,
                                             float* __restrict__ out) {
  int col = blockIdx.x * 256 + threadIdx.x;
  int b = blockIdx.y;                               // 0..31
  if (col >= NF) return;
  int nt = col >> 6, fl = col & 63;
  const float* Pt = P + ((size_t)(nt * 5) << 12);
  float re = 0.f, iv = 0.f;
#pragma unroll
  for (int c = 0; c < 5; ++c) {
    const float* Pb = Pt + ((size_t)c << 12);
    re += Pb[(2 * b) * 64 + fl];
    iv += Pb[(2 * b + 1) * 64 + fl];
  }
  out[(size_t)b * NF + col] = sqrtf(re * re + iv * iv);
}

extern "C" void kernel_launch(void* const* d_in, const int* in_sizes, int n_in,
                              void* d_out, int out_size, void* d_ws, size_t ws_size,
                              hipStream_t stream) {
  const float* x = (const float*)d_in[0];
  char* ws = (char*)d_ws;
  unsigned short* xb = (unsigned short*)(ws + XB_B);
  unsigned short* Ag = (unsigned short*)(ws + AG_B);
  float* P           = (float*)(ws + P_B);
  float* out = (float*)d_out;

  hipFuncSetAttribute((const void*)k_gemm,
                      hipFuncAttributeMaxDynamicSharedMemorySize, LDS_SZ);

  hipLaunchKernelGGL(k_prep, dim3(XB_NB + AG_NB), dim3(256), 0, stream, x, xb, Ag);
  hipLaunchKernelGGL(k_gemm, dim3(NBLK), dim3(256), LDS_SZ, stream, Ag, xb, P, out);
  hipLaunchKernelGGL(k_mag, dim3(20, 32), dim3(256), 0, stream, P, out);
}